// Round 7
// baseline (1130.384 us; speedup 1.0000x reference)
//
#include <hip/hip_runtime.h>
#include <hip/hip_bf16.h>
#include <cstdint>

// QuantizedLinear: Y[M,N] = X[M,K] . W^T + bias.  M=8192, N=16384, K=4096.
// INT8 path: W -> i8 exact; X -> per-row absmax i8 + row-sum (exact zp corr).
// GEMM mfma_i32_16x16x64_i8, 256x256 tile, BK=128, 8 waves (2x4).
// A: LDS-staged (xor-swizzled, 0-conflict), double-buffered 2x32KB.
// B: NO LDS — per-lane global_load_dwordx4 straight into MFMA B-frags
//    (B^T rows are K-contiguous; col-major-per-XCD grid keeps the shared
//    1MB B panel L2-resident).  DS pipe now carries A only -> MFMA-bound.
// 4-phase schedule, reads/loads one phase ahead, counted vmcnt/lgkm waits.

#define M_DIM 8192
#define N_DIM 16384
#define K_DIM 4096
#define BK    128
#define NT    (K_DIM / BK)   // 32 k-tiles

using i32x4 = __attribute__((ext_vector_type(4))) int;

// ---------------- prepass: X -> i8 per-row absmax ----------------
__global__ __launch_bounds__(256) void quant_x_kernel(const float* __restrict__ x,
                                                      signed char* __restrict__ xq,
                                                      float* __restrict__ rs1,
                                                      float* __restrict__ rs2) {
    const int row = blockIdx.x;
    const float* xr = x + (size_t)row * K_DIM;
    const int tid = threadIdx.x;

    float4 v[4];
    float amax = 0.f;
    #pragma unroll
    for (int j = 0; j < 4; ++j) {
        v[j] = *(const float4*)(xr + j * 1024 + tid * 4);
        amax = fmaxf(amax, fmaxf(fmaxf(fabsf(v[j].x), fabsf(v[j].y)),
                                 fmaxf(fabsf(v[j].z), fabsf(v[j].w))));
    }
    #pragma unroll
    for (int off = 32; off > 0; off >>= 1)
        amax = fmaxf(amax, __shfl_xor(amax, off));
    __shared__ float smax[4];
    __shared__ int   ssum[4];
    const int wv = tid >> 6, ln = tid & 63;
    if (ln == 0) smax[wv] = amax;
    __syncthreads();
    amax = fmaxf(fmaxf(smax[0], smax[1]), fmaxf(smax[2], smax[3]));
    const float s   = amax * (1.0f / 127.0f);
    const float inv = amax > 0.f ? 127.0f / amax : 0.f;

    int sum = 0;
    #pragma unroll
    for (int j = 0; j < 4; ++j) {
        int q0 = (int)__builtin_rintf(v[j].x * inv);
        int q1 = (int)__builtin_rintf(v[j].y * inv);
        int q2 = (int)__builtin_rintf(v[j].z * inv);
        int q3 = (int)__builtin_rintf(v[j].w * inv);
        sum += q0 + q1 + q2 + q3;
        int packed = (q0 & 255) | ((q1 & 255) << 8) | ((q2 & 255) << 16) | ((q3 & 255) << 24);
        *(int*)(xq + (size_t)row * K_DIM + j * 1024 + tid * 4) = packed;
    }
    #pragma unroll
    for (int off = 32; off > 0; off >>= 1)
        sum += __shfl_xor(sum, off);
    if (ln == 0) ssum[wv] = sum;
    __syncthreads();
    if (tid == 0) {
        int t = ssum[0] + ssum[1] + ssum[2] + ssum[3];
        rs1[row] = s;
        rs2[row] = s * (float)t;
    }
}

// ---------------- prepass: W int32 -> i8 (exact) ----------------
__global__ void quant_w_kernel(const int* __restrict__ q, signed char* __restrict__ o,
                               long long n) {
    long long i = ((long long)blockIdx.x * blockDim.x + threadIdx.x) * 4;
    const long long stride = (long long)gridDim.x * blockDim.x * 4;
    for (; i < n; i += stride) {
        int4 v = *(const int4*)(q + i);
        int packed = (v.x & 255) | ((v.y & 255) << 8) | ((v.z & 255) << 16) | ((v.w & 255) << 24);
        *(int*)(o + i) = packed;
    }
}

// ---------------- GEMM ----------------
#define SB() __builtin_amdgcn_sched_barrier(0)

__device__ __forceinline__ void barrier_() {
    SB();
    asm volatile("" ::: "memory");
    __builtin_amdgcn_s_barrier();
    asm volatile("" ::: "memory");
    SB();
}

// Stage one 128-row x 128-byte A half-tile (16 KiB) with 512 threads:
// 2 gload_lds w16; instr j covers rows j*64 + tid>>3.
// LDS[r][c16] = G[r][c16 ^ (r&7)] via inverse-swizzled global source.
__device__ __forceinline__ void stage_half(const signed char* g0, unsigned char* l0) {
    __builtin_amdgcn_global_load_lds((const __attribute__((address_space(1))) void*)g0,
                                     (__attribute__((address_space(3))) void*)l0, 16, 0, 0);
    __builtin_amdgcn_global_load_lds(
        (const __attribute__((address_space(1))) void*)(g0 + (size_t)64 * K_DIM),
        (__attribute__((address_space(3))) void*)(l0 + 8192), 16, 0, 0);
}

__global__ __launch_bounds__(512, 2) void gemm_i8_kernel(const signed char* __restrict__ A,
                                                         const signed char* __restrict__ B,
                                                         const float* __restrict__ rs1,
                                                         const float* __restrict__ rs2,
                                                         const float* __restrict__ scale,
                                                         const float* __restrict__ zpp,
                                                         const float* __restrict__ bias,
                                                         float* __restrict__ C) {
    extern __shared__ unsigned char smem[];   // 64 KiB: 2 bufs x A 32K bytes

    const int tid  = threadIdx.x;
    const int wave = tid >> 6;
    const int lane = tid & 63;
    const int fr = lane & 15, kq = lane >> 4;      // 16x16 frag: row/col = fr, k-slot = kq
    const int wr = wave >> 2, wc = wave & 3;       // wave tile 128x64 in 2x4 grid

    // Column-major-per-XCD grid: 2048 blocks; XCD c owns col-groups [c*8,(c+1)*8),
    // row varies fastest -> ~32 co-resident blocks/XCD share ONE 1MB B panel (L2).
    const int xcd = blockIdx.x & 7, idx = blockIdx.x >> 3;
    const int tileRow = (idx & 31) * 256;
    const int tileCol = (xcd * 8 + (idx >> 5)) * 256;

    // ---- A staging addressing (bytes) ----
    const size_t goff = (size_t)(tid >> 3) * K_DIM + (((tid & 7) ^ ((tid >> 3) & 7)) * 16);
    const signed char* Au  = A + (size_t)tileRow * K_DIM + goff;
    const signed char* AuH = Au + (size_t)128 * K_DIM;

    // ---- A read addressing (swizzled), byte offsets ----
    const int aoffB = wr * 16384 + fr * 128;            // + m*2048 + cs[ks]
    int cs[2];
    #pragma unroll
    for (int ks = 0; ks < 2; ++ks)
        cs[ks] = ((ks * 4 + kq) ^ (fr & 7)) * 16;

    // ---- B direct-load addressing: lane reads B^T[tileCol + wc*64 + n*16 + fr][k...]
    const signed char* Bv = B + (size_t)(tileCol + wc * 64 + fr) * K_DIM + kq * 16;

    i32x4 acc[8][4] = {};
    i32x4 arA[4][2], arB[4][2], bg0[2][2], bg1[2][2];

    // ---- prologue ----
    {
        unsigned char* w0 = smem + wave * 1024;
        unsigned char* w1 = smem + 32768 + wave * 1024;
        stage_half(Au,  w0);                // t0 Ah0
        stage_half(AuH, w0 + 16384);        // t0 Ah1
        SB();                                // pin t0 staging as the 4 oldest
        #pragma unroll
        for (int n = 0; n < 2; ++n)
            #pragma unroll
            for (int ks = 0; ks < 2; ++ks)
                bg0[n][ks] = *(const i32x4*)(Bv + (size_t)(n) * 16 * K_DIM + ks * 64);
        #pragma unroll
        for (int n = 0; n < 2; ++n)
            #pragma unroll
            for (int ks = 0; ks < 2; ++ks)
                bg1[n][ks] = *(const i32x4*)(Bv + (size_t)(n + 2) * 16 * K_DIM + ks * 64);
        SB();
        stage_half(Au + BK, w1);            // t1 Ah0
    }
    SB();
    asm volatile("s_waitcnt vmcnt(10)" ::: "memory");   // t0 A staged
    barrier_();
    #pragma unroll
    for (int m = 0; m < 4; ++m)
        #pragma unroll
        for (int ks = 0; ks < 2; ++ks)
            arA[m][ks] = *(const i32x4*)(smem + aoffB + m * 2048 + cs[ks]);
    SB();

    for (int t = 0; t < NT; ++t) {
        const unsigned char* sbr = smem + (t & 1) * 32768;
        const unsigned char* nxr = smem + ((t + 1) & 1) * 32768;
        unsigned char* sbw = smem + (t & 1) * 32768 + wave * 1024;
        unsigned char* nxw = smem + ((t + 1) & 1) * 32768 + wave * 1024;
        const int kn1 = (t + 1) * BK, kn2 = (t + 2) * BK;

        // ===== P1: stage Ah1(t+1); wait arA(t)+bg0(t); Q(m0-3, n0-1) =====
        if (t + 1 < NT) stage_half(AuH + kn1, nxw + 16384);
        SB();
        asm volatile("s_waitcnt lgkmcnt(0)" ::: "memory");
        if (t + 1 < NT) {
            asm volatile("s_waitcnt vmcnt(8)" ::: "memory");    // bg0(t) landed
        } else {
            asm volatile("s_waitcnt vmcnt(4)" ::: "memory");
        }
        SB();
        __builtin_amdgcn_s_setprio(1);
        #pragma unroll
        for (int ks = 0; ks < 2; ++ks)
            #pragma unroll
            for (int m = 0; m < 4; ++m)
                #pragma unroll
                for (int n = 0; n < 2; ++n)
                    acc[m][n] = __builtin_amdgcn_mfma_i32_16x16x64_i8(arA[m][ks], bg0[n][ks], acc[m][n], 0, 0, 0);
        __builtin_amdgcn_s_setprio(0);
        barrier_();

        // ===== P2: read arB(t) [ds, ahead]; wait bg1(t); Q(m0-3, n2-3) =====
        #pragma unroll
        for (int m = 0; m < 4; ++m)
            #pragma unroll
            for (int ks = 0; ks < 2; ++ks)
                arB[m][ks] = *(const i32x4*)(sbr + aoffB + (m + 4) * 2048 + cs[ks]);
        SB();
        if (t + 1 < NT) {
            asm volatile("s_waitcnt vmcnt(4)" ::: "memory");    // bg1(t) landed
        } else {
            asm volatile("s_waitcnt vmcnt(0)" ::: "memory");
        }
        SB();
        __builtin_amdgcn_s_setprio(1);
        #pragma unroll
        for (int ks = 0; ks < 2; ++ks)
            #pragma unroll
            for (int m = 0; m < 4; ++m)
                #pragma unroll
                for (int n = 0; n < 2; ++n)
                    acc[m][n + 2] = __builtin_amdgcn_mfma_i32_16x16x64_i8(arA[m][ks], bg1[n][ks], acc[m][n + 2], 0, 0, 0);
        __builtin_amdgcn_s_setprio(0);
        barrier_();

        // ===== P3: wait arB; Q(m4-7, n2-3); drain staging; barrier =====
        SB();
        asm volatile("s_waitcnt lgkmcnt(0)" ::: "memory");
        SB();
        __builtin_amdgcn_s_setprio(1);
        #pragma unroll
        for (int ks = 0; ks < 2; ++ks)
            #pragma unroll
            for (int m = 0; m < 4; ++m)
                #pragma unroll
                for (int n = 0; n < 2; ++n)
                    acc[m + 4][n + 2] = __builtin_amdgcn_mfma_i32_16x16x64_i8(arB[m][ks], bg1[n][ks], acc[m + 4][n + 2], 0, 0, 0);
        __builtin_amdgcn_s_setprio(0);
        SB();
        asm volatile("s_waitcnt vmcnt(0)" ::: "memory");   // A(t+1) fully staged
        barrier_();

        // ===== P4: read arA(t+1) [ds, ahead]; Q(m4-7, n0-1); then issue
        //           bg0(t+1), bg1(t+1) [WAR-safe after MFMA], stage Ah0(t+2) =====
        if (t + 1 < NT) {
            #pragma unroll
            for (int m = 0; m < 4; ++m)
                #pragma unroll
                for (int ks = 0; ks < 2; ++ks)
                    arA[m][ks] = *(const i32x4*)(nxr + aoffB + m * 2048 + cs[ks]);
        }
        SB();
        __builtin_amdgcn_s_setprio(1);
        #pragma unroll
        for (int ks = 0; ks < 2; ++ks)
            #pragma unroll
            for (int m = 0; m < 4; ++m)
                #pragma unroll
                for (int n = 0; n < 2; ++n)
                    acc[m + 4][n] = __builtin_amdgcn_mfma_i32_16x16x64_i8(arB[m][ks], bg0[n][ks], acc[m + 4][n], 0, 0, 0);
        __builtin_amdgcn_s_setprio(0);
        SB();
        if (t + 1 < NT) {
            #pragma unroll
            for (int n = 0; n < 2; ++n)
                #pragma unroll
                for (int ks = 0; ks < 2; ++ks)
                    bg0[n][ks] = *(const i32x4*)(Bv + (size_t)(n) * 16 * K_DIM + ks * 64 + kn1);
            #pragma unroll
            for (int n = 0; n < 2; ++n)
                #pragma unroll
                for (int ks = 0; ks < 2; ++ks)
                    bg1[n][ks] = *(const i32x4*)(Bv + (size_t)(n + 2) * 16 * K_DIM + ks * 64 + kn1);
        }
        SB();
        if (t + 2 < NT) stage_half(Au + kn2, sbw);
        SB();
        barrier_();
    }

    // ---- epilogue: 16x16 C/D layout col = lane&15, row = kq*4 + j ----
    const float sw  = scale[0];
    const float zpv = zpp[0];
    float bv[4];
    #pragma unroll
    for (int n = 0; n < 4; ++n)
        bv[n] = bias[tileCol + wc * 64 + n * 16 + fr];
    #pragma unroll
    for (int m = 0; m < 8; ++m) {
        #pragma unroll
        for (int j = 0; j < 4; ++j) {
            const int grow = tileRow + wr * 128 + m * 16 + kq * 4 + j;
            const float f1 = rs1[grow] * sw;
            const float f2 = zpv * rs2[grow] * sw;
            float* Crow = C + (size_t)grow * N_DIM + tileCol + wc * 64 + fr;
            #pragma unroll
            for (int n = 0; n < 4; ++n)
                Crow[n * 16] = f1 * (float)acc[m][n][j] - f2 + bv[n];
        }
    }
}

// Fallback (only if ws too small): basic LDS-tiled f32 GEMM.
__global__ void gemm_naive(const float* __restrict__ x, const int* __restrict__ wq,
                           const float* __restrict__ sp, const float* __restrict__ zp,
                           const float* __restrict__ bias, float* __restrict__ out) {
    __shared__ float sX[32][33];
    __shared__ float sW[32][33];
    const float s = sp[0], z = zp[0];
    const int tx = threadIdx.x & 15, ty = threadIdx.x >> 4;
    const int row0 = blockIdx.y * 32, col0 = blockIdx.x * 32;
    float acc[2][2] = {};
    for (int k0 = 0; k0 < K_DIM; k0 += 32) {
        for (int i = threadIdx.x; i < 32 * 32; i += 256) {
            int r = i >> 5, cc2 = i & 31;
            sX[r][cc2] = x[(size_t)(row0 + r) * K_DIM + k0 + cc2];
            sW[r][cc2] = ((float)wq[(size_t)(col0 + r) * K_DIM + k0 + cc2] - z) * s;
        }
        __syncthreads();
        #pragma unroll
        for (int k = 0; k < 32; ++k) {
            float xa0 = sX[ty * 2][k], xa1 = sX[ty * 2 + 1][k];
            float wb0 = sW[tx * 2][k], wb1 = sW[tx * 2 + 1][k];
            acc[0][0] += xa0 * wb0; acc[0][1] += xa0 * wb1;
            acc[1][0] += xa1 * wb0; acc[1][1] += xa1 * wb1;
        }
        __syncthreads();
    }
    #pragma unroll
    for (int i = 0; i < 2; ++i)
        #pragma unroll
        for (int j = 0; j < 2; ++j)
            out[(size_t)(row0 + ty * 2 + i) * N_DIM + (col0 + tx * 2 + j)] =
                acc[i][j] + bias[col0 + tx * 2 + j];
}

extern "C" void kernel_launch(void* const* d_in, const int* in_sizes, int n_in,
                              void* d_out, int out_size, void* d_ws, size_t ws_size,
                              hipStream_t stream) {
    const float* x     = (const float*)d_in[0];
    const int*   wq    = (const int*)d_in[1];
    const float* scale = (const float*)d_in[2];
    const float* zp    = (const float*)d_in[3];
    const float* bias  = (const float*)d_in[4];
    float* out = (float*)d_out;

    // ws layout: xq (32Mi) | wq8 (64Mi) | rs1 | rs2
    const size_t offXq = 0;
    const size_t offWq = (size_t)M_DIM * K_DIM;
    const size_t offR1 = offWq + (size_t)N_DIM * K_DIM;
    const size_t offR2 = offR1 + (size_t)M_DIM * sizeof(float);
    const size_t need  = offR2 + (size_t)M_DIM * sizeof(float);

    if (ws_size >= need) {
        signed char* xq  = (signed char*)d_ws + offXq;
        signed char* wq8 = (signed char*)d_ws + offWq;
        float* rs1 = (float*)((char*)d_ws + offR1);
        float* rs2 = (float*)((char*)d_ws + offR2);
        quant_x_kernel<<<M_DIM, 256, 0, stream>>>(x, xq, rs1, rs2);
        quant_w_kernel<<<4096, 256, 0, stream>>>(wq, wq8, (long long)N_DIM * K_DIM);
        (void)hipFuncSetAttribute((const void*)gemm_i8_kernel,
                                  hipFuncAttributeMaxDynamicSharedMemorySize, 65536);
        gemm_i8_kernel<<<(M_DIM / 256) * (N_DIM / 256), 512, 65536, stream>>>(
            xq, wq8, rs1, rs2, scale, zp, bias, out);
    } else {
        dim3 grid(N_DIM / 32, M_DIM / 32);
        gemm_naive<<<grid, 256, 0, stream>>>(x, wq, scale, zp, bias, out);
    }
}

// Round 9
// 632.358 us; speedup vs baseline: 1.7876x; 1.7876x over previous
//
#include <hip/hip_runtime.h>
#include <hip/hip_bf16.h>
#include <cstdint>

// QuantizedLinear: Y[M,N] = X[M,K] . W^T + bias.  M=8192, N=16384, K=4096.
// INT8 path: W -> i8 exact; X -> per-row absmax i8 + row-sum (exact zp corr).
// GEMM mfma_i32_16x16x64_i8, 256x256 tile, BK=128, 8 waves (2x4), 128KiB LDS
// dbuf.  R6-verified schedule (reads one phase ahead, counted lgkm; staging
// only after the barrier that follows lgkm-retirement of the region's readers):
//   P1: issue b1r(t);            lgkm(4);  Q00; bar
//   P2: issue arB(t);            lgkm(8);  Q01; bar
//   P3: stage B(t+2);            lgkm(0);  Q11; vmcnt(4); bar
//   P4: read arA(t+1); stage Ah0+Ah1(t+2); Q10; read b0r(t+1); bar
// (vs R6: Ah1(t+1) staging moved P1(t) -> P4(t-1): legal — its region's last
//  reader arB(t-1) retired at P3(t-1) — and gives the whole next tile >=3
//  phases of staging slack before the single counted vmcnt(4).)
// T2 xor-swizzle (0 conflicts), T5 setprio, XCD-swizzled grid.

#define M_DIM 8192
#define N_DIM 16384
#define K_DIM 4096
#define BK    128
#define NT    (K_DIM / BK)   // 32 k-tiles

using i32x4 = __attribute__((ext_vector_type(4))) int;

// ---------------- prepass: X -> i8 per-row absmax ----------------
__global__ __launch_bounds__(256) void quant_x_kernel(const float* __restrict__ x,
                                                      signed char* __restrict__ xq,
                                                      float* __restrict__ rs1,
                                                      float* __restrict__ rs2) {
    const int row = blockIdx.x;
    const float* xr = x + (size_t)row * K_DIM;
    const int tid = threadIdx.x;

    float4 v[4];
    float amax = 0.f;
    #pragma unroll
    for (int j = 0; j < 4; ++j) {
        v[j] = *(const float4*)(xr + j * 1024 + tid * 4);
        amax = fmaxf(amax, fmaxf(fmaxf(fabsf(v[j].x), fabsf(v[j].y)),
                                 fmaxf(fabsf(v[j].z), fabsf(v[j].w))));
    }
    #pragma unroll
    for (int off = 32; off > 0; off >>= 1)
        amax = fmaxf(amax, __shfl_xor(amax, off));
    __shared__ float smax[4];
    __shared__ int   ssum[4];
    const int wv = tid >> 6, ln = tid & 63;
    if (ln == 0) smax[wv] = amax;
    __syncthreads();
    amax = fmaxf(fmaxf(smax[0], smax[1]), fmaxf(smax[2], smax[3]));
    const float s   = amax * (1.0f / 127.0f);
    const float inv = amax > 0.f ? 127.0f / amax : 0.f;

    int sum = 0;
    #pragma unroll
    for (int j = 0; j < 4; ++j) {
        int q0 = (int)__builtin_rintf(v[j].x * inv);
        int q1 = (int)__builtin_rintf(v[j].y * inv);
        int q2 = (int)__builtin_rintf(v[j].z * inv);
        int q3 = (int)__builtin_rintf(v[j].w * inv);
        sum += q0 + q1 + q2 + q3;
        int packed = (q0 & 255) | ((q1 & 255) << 8) | ((q2 & 255) << 16) | ((q3 & 255) << 24);
        *(int*)(xq + (size_t)row * K_DIM + j * 1024 + tid * 4) = packed;
    }
    #pragma unroll
    for (int off = 32; off > 0; off >>= 1)
        sum += __shfl_xor(sum, off);
    if (ln == 0) ssum[wv] = sum;
    __syncthreads();
    if (tid == 0) {
        int t = ssum[0] + ssum[1] + ssum[2] + ssum[3];
        rs1[row] = s;
        rs2[row] = s * (float)t;
    }
}

// ---------------- prepass: W int32 -> i8 (exact) ----------------
__global__ void quant_w_kernel(const int* __restrict__ q, signed char* __restrict__ o,
                               long long n) {
    long long i = ((long long)blockIdx.x * blockDim.x + threadIdx.x) * 4;
    const long long stride = (long long)gridDim.x * blockDim.x * 4;
    for (; i < n; i += stride) {
        int4 v = *(const int4*)(q + i);
        int packed = (v.x & 255) | ((v.y & 255) << 8) | ((v.z & 255) << 16) | ((v.w & 255) << 24);
        *(int*)(o + i) = packed;
    }
}

// ---------------- GEMM ----------------
#define SB() __builtin_amdgcn_sched_barrier(0)

__device__ __forceinline__ void barrier_() {
    SB();
    asm volatile("" ::: "memory");
    __builtin_amdgcn_s_barrier();
    asm volatile("" ::: "memory");
    SB();
}

// Stage one 128-row x 128-byte half-tile (16 KiB) with 512 threads:
// 2 gload_lds w16; instr j covers rows j*64 + tid>>3.
// LDS[r][c16] = G[r][c16 ^ (r&7)] via inverse-swizzled global source.
__device__ __forceinline__ void stage_half(const signed char* g0, unsigned char* l0) {
    __builtin_amdgcn_global_load_lds((const __attribute__((address_space(1))) void*)g0,
                                     (__attribute__((address_space(3))) void*)l0, 16, 0, 0);
    __builtin_amdgcn_global_load_lds(
        (const __attribute__((address_space(1))) void*)(g0 + (size_t)64 * K_DIM),
        (__attribute__((address_space(3))) void*)(l0 + 8192), 16, 0, 0);
}

__global__ __launch_bounds__(512, 2) void gemm_i8_kernel(const signed char* __restrict__ A,
                                                         const signed char* __restrict__ B,
                                                         const float* __restrict__ rs1,
                                                         const float* __restrict__ rs2,
                                                         const float* __restrict__ scale,
                                                         const float* __restrict__ zpp,
                                                         const float* __restrict__ bias,
                                                         float* __restrict__ C) {
    extern __shared__ unsigned char smem[];   // 128 KiB: 2 bufs x (A 32K + B 32K bytes)

    const int tid  = threadIdx.x;
    const int wave = tid >> 6;
    const int lane = tid & 63;
    const int fr = lane & 15, kq = lane >> 4;      // 16x16 frag: row/col = fr, k-slot = kq
    const int wr = wave >> 2, wc = wave & 3;       // wave tile 128x64 in 2x4 grid

    // XCD-aware bijective swizzle: nwg = 2048, divisible by 8.
    const int swz = (blockIdx.x & 7) * 256 + (blockIdx.x >> 3);
    const int ntn = N_DIM / 256;
    const int tileRow = (swz / ntn) * 256;
    const int tileCol = (swz % ntn) * 256;

    // ---- staging addressing (bytes) ----
    const size_t goff = (size_t)(tid >> 3) * K_DIM + (((tid & 7) ^ ((tid >> 3) & 7)) * 16);
    const signed char* Au  = A + (size_t)tileRow * K_DIM + goff;
    const signed char* Bu  = B + (size_t)tileCol * K_DIM + goff;
    const signed char* AuH = Au + (size_t)128 * K_DIM;
    const signed char* BuH = Bu + (size_t)128 * K_DIM;

    // ---- read addressing (swizzled), byte offsets ----
    const int aoffB = wr * 16384 + fr * 128;            // + m*2048 + cs[ks]
    const int boffB = 32768 + wc * 8192 + fr * 128;     // + n*2048 + cs[ks]
    int cs[2];
    #pragma unroll
    for (int ks = 0; ks < 2; ++ks)
        cs[ks] = ((ks * 4 + kq) ^ (fr & 7)) * 16;

    i32x4 acc[8][4] = {};
    i32x4 arA[4][2], arB[4][2], b0r[2][2], b1r[2][2];

    // ---- prologue: stage t0 (8 halves) + t1 (8 halves); vmcnt(8) -> t0 landed ----
    {
        unsigned char* w0 = smem + wave * 1024;
        unsigned char* w1 = smem + 65536 + wave * 1024;
        stage_half(Au,  w0);                // t0 Ah0
        stage_half(AuH, w0 + 16384);        // t0 Ah1
        stage_half(Bu,  w0 + 32768);        // t0 Bh0
        stage_half(BuH, w0 + 49152);        // t0 Bh1
        stage_half(Bu + BK,  w1 + 32768);   // t1 Bh0
        stage_half(BuH + BK, w1 + 49152);   // t1 Bh1
        stage_half(Au + BK,  w1);           // t1 Ah0
        stage_half(AuH + BK, w1 + 16384);   // t1 Ah1
    }
    SB();
    asm volatile("s_waitcnt vmcnt(8)" ::: "memory");   // tile0 landed
    barrier_();
    // boundary reads for t=0: arA (m0-3) then b0r (n0-1)
    #pragma unroll
    for (int m = 0; m < 4; ++m)
        #pragma unroll
        for (int ks = 0; ks < 2; ++ks)
            arA[m][ks] = *(const i32x4*)(smem + aoffB + m * 2048 + cs[ks]);
    #pragma unroll
    for (int n = 0; n < 2; ++n)
        #pragma unroll
        for (int ks = 0; ks < 2; ++ks)
            b0r[n][ks] = *(const i32x4*)(smem + boffB + n * 2048 + cs[ks]);
    SB();

    for (int t = 0; t < NT; ++t) {
        const unsigned char* sbr = smem + (t & 1) * 65536;
        const unsigned char* nxr = smem + ((t + 1) & 1) * 65536;
        unsigned char* sbw = smem + (t & 1) * 65536 + wave * 1024;   // t+2 staging
        const int kn2 = (t + 2) * BK;

        // ===== P1: issue b1r(t); lgkm(4)[arA,b0r ready]; Q00(arA x b0r); bar =====
        #pragma unroll
        for (int n = 0; n < 2; ++n)
            #pragma unroll
            for (int ks = 0; ks < 2; ++ks)
                b1r[n][ks] = *(const i32x4*)(sbr + boffB + (n + 2) * 2048 + cs[ks]);
        SB();
        asm volatile("s_waitcnt lgkmcnt(4)" ::: "memory");
        SB();
        __builtin_amdgcn_s_setprio(1);
        #pragma unroll
        for (int ks = 0; ks < 2; ++ks)
            #pragma unroll
            for (int m = 0; m < 4; ++m)
                #pragma unroll
                for (int n = 0; n < 2; ++n)
                    acc[m][n] = __builtin_amdgcn_mfma_i32_16x16x64_i8(arA[m][ks], b0r[n][ks], acc[m][n], 0, 0, 0);
        __builtin_amdgcn_s_setprio(0);
        barrier_();

        // ===== P2: issue arB(t); lgkm(8)[b1r ready]; Q01(arA x b1r); bar =====
        #pragma unroll
        for (int m = 0; m < 4; ++m)
            #pragma unroll
            for (int ks = 0; ks < 2; ++ks)
                arB[m][ks] = *(const i32x4*)(sbr + aoffB + (m + 4) * 2048 + cs[ks]);
        SB();
        asm volatile("s_waitcnt lgkmcnt(8)" ::: "memory");
        SB();
        __builtin_amdgcn_s_setprio(1);
        #pragma unroll
        for (int ks = 0; ks < 2; ++ks)
            #pragma unroll
            for (int m = 0; m < 4; ++m)
                #pragma unroll
                for (int n = 0; n < 2; ++n)
                    acc[m][n + 2] = __builtin_amdgcn_mfma_i32_16x16x64_i8(arA[m][ks], b1r[n][ks], acc[m][n + 2], 0, 0, 0);
        __builtin_amdgcn_s_setprio(0);
        barrier_();

        // ===== P3: stage Bh0+Bh1(t+2) [b0r/b1r(t) retired + barrier passed];
        //           lgkm(0)[arB ready]; Q11; counted vmcnt(4); bar =====
        if (t + 2 < NT) {
            stage_half(Bu + kn2,  sbw + 32768);
            stage_half(BuH + kn2, sbw + 49152);
        }
        SB();
        asm volatile("s_waitcnt lgkmcnt(0)" ::: "memory");
        SB();
        __builtin_amdgcn_s_setprio(1);
        #pragma unroll
        for (int ks = 0; ks < 2; ++ks)
            #pragma unroll
            for (int m = 0; m < 4; ++m)
                #pragma unroll
                for (int n = 0; n < 2; ++n)
                    acc[m + 4][n + 2] = __builtin_amdgcn_mfma_i32_16x16x64_i8(arB[m][ks], b1r[n][ks], acc[m + 4][n + 2], 0, 0, 0);
        __builtin_amdgcn_s_setprio(0);
        SB();
        if (t + 2 < NT) {
            asm volatile("s_waitcnt vmcnt(4)" ::: "memory");   // tile t+1 fully landed
        } else {
            asm volatile("s_waitcnt vmcnt(0)" ::: "memory");   // tail drain
        }
        barrier_();

        // ===== P4: read arA(t+1); stage Ah0+Ah1(t+2) [arA/arB(t) retired +
        //           barrier passed]; Q10(arB x b0r); read b0r(t+1) post-MFMA; bar =====
        if (t + 1 < NT) {
            #pragma unroll
            for (int m = 0; m < 4; ++m)
                #pragma unroll
                for (int ks = 0; ks < 2; ++ks)
                    arA[m][ks] = *(const i32x4*)(nxr + aoffB + m * 2048 + cs[ks]);
        }
        if (t + 2 < NT) {
            stage_half(Au + kn2,  sbw);
            stage_half(AuH + kn2, sbw + 16384);
        }
        SB();
        __builtin_amdgcn_s_setprio(1);
        #pragma unroll
        for (int ks = 0; ks < 2; ++ks)
            #pragma unroll
            for (int m = 0; m < 4; ++m)
                #pragma unroll
                for (int n = 0; n < 2; ++n)
                    acc[m + 4][n] = __builtin_amdgcn_mfma_i32_16x16x64_i8(arB[m][ks], b0r[n][ks], acc[m + 4][n], 0, 0, 0);
        __builtin_amdgcn_s_setprio(0);
        SB();
        if (t + 1 < NT) {   // WAR-safe: after Q10 consumed b0r
            #pragma unroll
            for (int n = 0; n < 2; ++n)
                #pragma unroll
                for (int ks = 0; ks < 2; ++ks)
                    b0r[n][ks] = *(const i32x4*)(nxr + boffB + n * 2048 + cs[ks]);
        }
        SB();
        barrier_();
    }

    // ---- epilogue: 16x16 C/D layout col = lane&15, row = kq*4 + j ----
    const float sw  = scale[0];
    const float zpv = zpp[0];
    float bv[4];
    #pragma unroll
    for (int n = 0; n < 4; ++n)
        bv[n] = bias[tileCol + wc * 64 + n * 16 + fr];
    #pragma unroll
    for (int m = 0; m < 8; ++m) {
        #pragma unroll
        for (int j = 0; j < 4; ++j) {
            const int grow = tileRow + wr * 128 + m * 16 + kq * 4 + j;
            const float f1 = rs1[grow] * sw;
            const float f2 = zpv * rs2[grow] * sw;
            float* Crow = C + (size_t)grow * N_DIM + tileCol + wc * 64 + fr;
            #pragma unroll
            for (int n = 0; n < 4; ++n)
                Crow[n * 16] = f1 * (float)acc[m][n][j] - f2 + bv[n];
        }
    }
}

// Fallback (only if ws too small): basic LDS-tiled f32 GEMM.
__global__ void gemm_naive(const float* __restrict__ x, const int* __restrict__ wq,
                           const float* __restrict__ sp, const float* __restrict__ zp,
                           const float* __restrict__ bias, float* __restrict__ out) {
    __shared__ float sX[32][33];
    __shared__ float sW[32][33];
    const float s = sp[0], z = zp[0];
    const int tx = threadIdx.x & 15, ty = threadIdx.x >> 4;
    const int row0 = blockIdx.y * 32, col0 = blockIdx.x * 32;
    float acc[2][2] = {};
    for (int k0 = 0; k0 < K_DIM; k0 += 32) {
        for (int i = threadIdx.x; i < 32 * 32; i += 256) {
            int r = i >> 5, cc2 = i & 31;
            sX[r][cc2] = x[(size_t)(row0 + r) * K_DIM + k0 + cc2];
            sW[r][cc2] = ((float)wq[(size_t)(col0 + r) * K_DIM + k0 + cc2] - z) * s;
        }
        __syncthreads();
        #pragma unroll
        for (int k = 0; k < 32; ++k) {
            float xa0 = sX[ty * 2][k], xa1 = sX[ty * 2 + 1][k];
            float wb0 = sW[tx * 2][k], wb1 = sW[tx * 2 + 1][k];
            acc[0][0] += xa0 * wb0; acc[0][1] += xa0 * wb1;
            acc[1][0] += xa1 * wb0; acc[1][1] += xa1 * wb1;
        }
        __syncthreads();
    }
    #pragma unroll
    for (int i = 0; i < 2; ++i)
        #pragma unroll
        for (int j = 0; j < 2; ++j)
            out[(size_t)(row0 + ty * 2 + i) * N_DIM + (col0 + tx * 2 + j)] =
                acc[i][j] + bias[col0 + tx * 2 + j];
}

extern "C" void kernel_launch(void* const* d_in, const int* in_sizes, int n_in,
                              void* d_out, int out_size, void* d_ws, size_t ws_size,
                              hipStream_t stream) {
    const float* x     = (const float*)d_in[0];
    const int*   wq    = (const int*)d_in[1];
    const float* scale = (const float*)d_in[2];
    const float* zp    = (const float*)d_in[3];
    const float* bias  = (const float*)d_in[4];
    float* out = (float*)d_out;

    // ws layout: xq (32Mi) | wq8 (64Mi) | rs1 | rs2
    const size_t offXq = 0;
    const size_t offWq = (size_t)M_DIM * K_DIM;
    const size_t offR1 = offWq + (size_t)N_DIM * K_DIM;
    const size_t offR2 = offR1 + (size_t)M_DIM * sizeof(float);
    const size_t need  = offR2 + (size_t)M_DIM * sizeof(float);

    if (ws_size >= need) {
        signed char* xq  = (signed char*)d_ws + offXq;
        signed char* wq8 = (signed char*)d_ws + offWq;
        float* rs1 = (float*)((char*)d_ws + offR1);
        float* rs2 = (float*)((char*)d_ws + offR2);
        quant_x_kernel<<<M_DIM, 256, 0, stream>>>(x, xq, rs1, rs2);
        quant_w_kernel<<<4096, 256, 0, stream>>>(wq, wq8, (long long)N_DIM * K_DIM);
        (void)hipFuncSetAttribute((const void*)gemm_i8_kernel,
                                  hipFuncAttributeMaxDynamicSharedMemorySize, 131072);
        gemm_i8_kernel<<<(M_DIM / 256) * (N_DIM / 256), 512, 131072, stream>>>(
            xq, wq8, rs1, rs2, scale, zp, bias, out);
    } else {
        dim3 grid(N_DIM / 32, M_DIM / 32);
        gemm_naive<<<grid, 256, 0, stream>>>(x, wq, scale, zp, bias, out);
    }
}